// Round 1
// baseline (431.965 us; speedup 1.0000x reference)
//
#include <hip/hip_runtime.h>
#include <math.h>

#define T_STEPS 730
#define NB      1000
#define NMULT   8
#define LENF    15
#define NEARZ   1e-5f

// ---------------------------------------------------------------------------
// Kernel 0: gamma unit hydrograph, transposed layout UH_T[k*NB + b].
// gammaln(aa) and aa*log(theta) cancel under normalization:
//   w_k ∝ t_k^(aa-1) * exp(-t_k/theta)
// ---------------------------------------------------------------------------
__global__ __launch_bounds__(256) void uh_kernel(const float* __restrict__ raw,
                                                 float* __restrict__ uh) {
    int b = blockIdx.x * 256 + threadIdx.x;
    if (b >= NB) return;
    float ra = raw[b * 34 + 32] * 2.9f;          // RA_LO=0
    float rb = raw[b * 34 + 33] * 6.5f;          // RB_LO=0
    float aa = fmaxf(ra, 0.0f) + 0.1f;
    float th = fmaxf(rb, 0.0f) + 0.5f;
    float inv_th = 1.0f / th;
    float am1 = aa - 1.0f;
    float w[LENF];
    float s = 0.0f;
#pragma unroll
    for (int k = 0; k < LENF; ++k) {
        float t = (float)k + 0.5f;
        float lw = am1 * __logf(t) - t * inv_th;
        w[k] = __expf(lw);
        s += w[k];
    }
    float invs = 1.0f / s;
#pragma unroll
    for (int k = 0; k < LENF; ++k) uh[k * NB + b] = w[k] * invs;
}

// ---------------------------------------------------------------------------
// Kernel 1: the T=730 sequential scan. One thread per (basin, mul) chain;
// 8 consecutive lanes share a basin. Cross-NMUL means via 3-stage shfl_xor.
// Writes AET/S/G means directly to out ch3..5; Qsurf/Qgw means to ws for
// routing. (Qsim conv = Qsurf conv + Qgw conv by linearity — ch0 derived.)
// block=64 (one wave), grid=125 → spread across CUs; latency-bound chain.
// ---------------------------------------------------------------------------
__global__ __launch_bounds__(64) void scan_kernel(const float* __restrict__ x,
                                                  const float* __restrict__ raw,
                                                  float* __restrict__ out,
                                                  float* __restrict__ qsurf_ws,
                                                  float* __restrict__ qgw_ws) {
    int tid = blockIdx.x * 64 + threadIdx.x;   // 0..7999 exactly (125*64)
    int b = tid >> 3;
    int m = tid & 7;

    // parameter descaling: raw (B,34) = [a(8), b(8), c(8), d(8), ra, rb]
    const float* rp = raw + b * 34;
    float pa = rp[0 * NMULT + m] * 0.9f + 0.1f;     // A in [0.1, 1.0]
    float pb = rp[1 * NMULT + m] * 450.0f + 50.0f;  // B in [50, 500]
    float pc = rp[2 * NMULT + m];                   // C in [0, 1]
    float pd = rp[3 * NMULT + m] * 0.89f + 0.01f;   // D in [0.01, 0.9]

    float inv2a  = 1.0f / (2.0f * pa);
    float boa    = pb / pa;
    float invb   = 1.0f / pb;
    float omc    = 1.0f - pc;
    float inv1pd = 1.0f / (1.0f + pd);

    float S = 50.0f, G = 10.0f;

    for (int t = 0; t < T_STEPS; ++t) {
        float p   = x[(t * NB + b) * 2 + 0];
        float pet = x[(t * NB + b) * 2 + 1];

        float W     = p + S;
        float term  = (W + pb) * inv2a;
        float disc  = fmaxf(term * term - W * boa, NEARZ);
        float Y     = term - sqrtf(disc);
        float e     = __expf(-pet * invb);       // off the S-chain
        float Sn    = Y * e;
        float AET   = Y - Sn;
        float avail = W - Y;
        float Qsurf = omc * avail;
        float Gn    = (G + pc * avail) * inv1pd;
        float Qgw   = pd * Gn;
        S = Sn; G = Gn;

        // reduce across the 8 lanes of this basin (results land in all 8)
        float r0 = Qsurf, r1 = Qgw, r2 = AET, r3 = Sn, r4 = Gn;
        r0 += __shfl_xor(r0, 1); r0 += __shfl_xor(r0, 2); r0 += __shfl_xor(r0, 4);
        r1 += __shfl_xor(r1, 1); r1 += __shfl_xor(r1, 2); r1 += __shfl_xor(r1, 4);
        r2 += __shfl_xor(r2, 1); r2 += __shfl_xor(r2, 2); r2 += __shfl_xor(r2, 4);
        r3 += __shfl_xor(r3, 1); r3 += __shfl_xor(r3, 2); r3 += __shfl_xor(r3, 4);
        r4 += __shfl_xor(r4, 1); r4 += __shfl_xor(r4, 2); r4 += __shfl_xor(r4, 4);

        if (m == 0) {
            qsurf_ws[t * NB + b] = r0 * 0.125f;
            qgw_ws  [t * NB + b] = r1 * 0.125f;
            float* o = out + (t * NB + b) * 6;
            o[3] = r2 * 0.125f;
            o[4] = r3 * 0.125f;
            o[5] = r4 * 0.125f;
        }
    }
}

// ---------------------------------------------------------------------------
// Kernel 2: 15-tap causal convolution per (t, basin); writes out ch0..2.
// Reads coalesced across b (q stored [t*NB+b], UH stored [k*NB+b]).
// ---------------------------------------------------------------------------
__global__ __launch_bounds__(256) void conv_kernel(const float* __restrict__ qsurf_ws,
                                                   const float* __restrict__ qgw_ws,
                                                   const float* __restrict__ uh,
                                                   float* __restrict__ out) {
    int b = blockIdx.x * 256 + threadIdx.x;
    int t = blockIdx.y;
    if (b >= NB) return;
    float ys = 0.0f, yg = 0.0f;
    int kmax = t < (LENF - 1) ? t : (LENF - 1);
    for (int k = 0; k <= kmax; ++k) {
        float w = uh[k * NB + b];
        ys = fmaf(qsurf_ws[(t - k) * NB + b], w, ys);
        yg = fmaf(qgw_ws  [(t - k) * NB + b], w, yg);
    }
    float* o = out + (t * NB + b) * 6;
    o[0] = ys + yg;
    o[1] = ys;
    o[2] = yg;
}

// ---------------------------------------------------------------------------
extern "C" void kernel_launch(void* const* d_in, const int* in_sizes, int n_in,
                              void* d_out, int out_size, void* d_ws, size_t ws_size,
                              hipStream_t stream) {
    const float* x   = (const float*)d_in[0];   // (T,B,2) fp32
    const float* raw = (const float*)d_in[1];   // (B,34)  fp32
    float* out = (float*)d_out;                 // (T,B,6) fp32

    // workspace layout (floats): qsurf[T*B] | qgw[T*B] | uh[15*B]  (~5.9 MB)
    float* qs = (float*)d_ws;
    float* qg = qs + (size_t)T_STEPS * NB;
    float* uh = qg + (size_t)T_STEPS * NB;

    uh_kernel<<<dim3((NB + 255) / 256), dim3(256), 0, stream>>>(raw, uh);
    scan_kernel<<<dim3((NB * NMULT) / 64), dim3(64), 0, stream>>>(x, raw, out, qs, qg);
    conv_kernel<<<dim3((NB + 255) / 256, T_STEPS), dim3(256), 0, stream>>>(qs, qg, uh, out);
}

// Round 3
// 287.327 us; speedup vs baseline: 1.5034x; 1.5034x over previous
//
#include <hip/hip_runtime.h>
#include <math.h>

#define T_STEPS 730
#define NB      1000
#define NMULT   8
#define LENF    15
#define NEARZ   1e-5f

// ---------------------------------------------------------------------------
// DPP helpers: butterfly sum over each aligned group of 8 lanes, pure VALU.
// quad_perm[1,0,3,2]=0xB1 (xor1), quad_perm[2,3,0,1]=0x4E (xor2),
// row_half_mirror=0x141 (lane i <-> (i&~7)|(7-(i&7)), i.e. cross-half of 8).
// ---------------------------------------------------------------------------
template <int CTRL>
__device__ __forceinline__ float dpp_mov(float x) {
    int xi = __builtin_bit_cast(int, x);
    int r  = __builtin_amdgcn_update_dpp(0, xi, CTRL, 0xF, 0xF, true);
    return __builtin_bit_cast(float, r);
}
__device__ __forceinline__ float sum8(float v) {
    v += dpp_mov<0xB1>(v);
    v += dpp_mov<0x4E>(v);
    v += dpp_mov<0x141>(v);
    return v;   // all 8 lanes of the group hold the group sum
}

// ---------------------------------------------------------------------------
// Kernel 0: gamma unit hydrograph, transposed layout UH_T[k*NB + b].
// gammaln(aa) and aa*log(theta) cancel under normalization:
//   w_k ∝ t_k^(aa-1) * exp(-t_k/theta)
// ---------------------------------------------------------------------------
__global__ __launch_bounds__(256) void uh_kernel(const float* __restrict__ raw,
                                                 float* __restrict__ uh) {
    int b = blockIdx.x * 256 + threadIdx.x;
    if (b >= NB) return;
    float ra = raw[b * 34 + 32] * 2.9f;
    float rb = raw[b * 34 + 33] * 6.5f;
    float aa = fmaxf(ra, 0.0f) + 0.1f;
    float th = fmaxf(rb, 0.0f) + 0.5f;
    float inv_th = 1.0f / th;
    float am1 = aa - 1.0f;
    float w[LENF];
    float s = 0.0f;
#pragma unroll
    for (int k = 0; k < LENF; ++k) {
        float t = (float)k + 0.5f;
        float lw = am1 * __logf(t) - t * inv_th;
        w[k] = __expf(lw);
        s += w[k];
    }
    float invs = 1.0f / s;
#pragma unroll
    for (int k = 0; k < LENF; ++k) uh[k * NB + b] = w[k] * invs;
}

// ---------------------------------------------------------------------------
// Kernel 1: the T=730 sequential scan. One thread per (basin, mul) chain;
// 8 consecutive lanes share a basin. Cross-NMUL means via DPP butterfly
// (VALU-rate, no LDS pipe). x loads 2-deep software-prefetched as float2
// so L2-hit latency (~200cy) overlaps two iterations of compute.
// ---------------------------------------------------------------------------
__global__ __launch_bounds__(64) void scan_kernel(const float* __restrict__ x,
                                                  const float* __restrict__ raw,
                                                  float* __restrict__ out,
                                                  float* __restrict__ qsurf_ws,
                                                  float* __restrict__ qgw_ws) {
    int tid = blockIdx.x * 64 + threadIdx.x;   // 0..7999 exactly (125*64)
    int b = tid >> 3;
    int m = tid & 7;

    // parameter descaling: raw (B,34) = [a(8), b(8), c(8), d(8), ra, rb]
    const float* rp = raw + b * 34;
    float pa = rp[0 * NMULT + m] * 0.9f + 0.1f;     // A in [0.1, 1.0]
    float pb = rp[1 * NMULT + m] * 450.0f + 50.0f;  // B in [50, 500]
    float pc = rp[2 * NMULT + m];                   // C in [0, 1]
    float pd = rp[3 * NMULT + m] * 0.89f + 0.01f;   // D in [0.01, 0.9]

    float inv2a   = 1.0f / (2.0f * pa);
    float pb2a    = pb * inv2a;                     // term = fma(W, inv2a, pb2a)
    float boa     = pb / pa;
    float ninvbl2 = -1.4426950408889634f / pb;      // exp(-pet/b) = exp2(pet*ninvbl2)
    float omc     = 1.0f - pc;
    float inv1pd  = 1.0f / (1.0f + pd);

    float S = 50.0f, G = 10.0f;

    const float2* __restrict__ xf = (const float2*)x;  // (T,B) of (p,pet)

    float2 x0 = xf[0 * NB + b];
    float2 x1 = xf[1 * NB + b];

    for (int t = 0; t < T_STEPS; ++t) {
        // 2-deep prefetch (issue before the dependent compute)
        int tn = t + 2; if (tn > T_STEPS - 1) tn = T_STEPS - 1;
        float2 x2 = xf[tn * NB + b];

        float p = x0.x, pet = x0.y;

        float W     = p + S;
        float term  = fmaf(W, inv2a, pb2a);
        float wboa  = W * boa;
        float disc  = fmaf(term, term, -wboa);
        float r     = sqrtf(fmaxf(disc, NEARZ));
        float Y     = term - r;
        float e     = __builtin_amdgcn_exp2f(pet * ninvbl2);  // off the S-chain
        float Sn    = Y * e;
        float AET   = Y - Sn;
        float avail = W - Y;
        float Qsurf = omc * avail;
        float Gn    = fmaf(pc, avail, G) * inv1pd;
        float Qgw   = pd * Gn;
        S = Sn; G = Gn;

        float r0 = sum8(Qsurf);
        float r1 = sum8(Qgw);
        float r2 = sum8(AET);
        float r3 = sum8(Sn);
        float r4 = sum8(Gn);

        if (m == 0) {
            qsurf_ws[t * NB + b] = r0 * 0.125f;
            qgw_ws  [t * NB + b] = r1 * 0.125f;
            float* o = out + (t * NB + b) * 6;
            o[3] = r2 * 0.125f;
            o[4] = r3 * 0.125f;
            o[5] = r4 * 0.125f;
        }

        x0 = x1; x1 = x2;
    }
}

// ---------------------------------------------------------------------------
// Kernel 2: 15-tap causal convolution per (t, basin); writes out ch0..2.
// Qsim conv = Qsurf conv + Qgw conv by linearity.
// ---------------------------------------------------------------------------
__global__ __launch_bounds__(256) void conv_kernel(const float* __restrict__ qsurf_ws,
                                                   const float* __restrict__ qgw_ws,
                                                   const float* __restrict__ uh,
                                                   float* __restrict__ out) {
    int b = blockIdx.x * 256 + threadIdx.x;
    int t = blockIdx.y;
    if (b >= NB) return;
    float ys = 0.0f, yg = 0.0f;
    int kmax = t < (LENF - 1) ? t : (LENF - 1);
    for (int k = 0; k <= kmax; ++k) {
        float w = uh[k * NB + b];
        ys = fmaf(qsurf_ws[(t - k) * NB + b], w, ys);
        yg = fmaf(qgw_ws  [(t - k) * NB + b], w, yg);
    }
    float* o = out + (t * NB + b) * 6;
    o[0] = ys + yg;
    o[1] = ys;
    o[2] = yg;
}

// ---------------------------------------------------------------------------
extern "C" void kernel_launch(void* const* d_in, const int* in_sizes, int n_in,
                              void* d_out, int out_size, void* d_ws, size_t ws_size,
                              hipStream_t stream) {
    const float* x   = (const float*)d_in[0];   // (T,B,2) fp32
    const float* raw = (const float*)d_in[1];   // (B,34)  fp32
    float* out = (float*)d_out;                 // (T,B,6) fp32

    // workspace layout (floats): qsurf[T*B] | qgw[T*B] | uh[15*B]  (~5.9 MB)
    float* qs = (float*)d_ws;
    float* qg = qs + (size_t)T_STEPS * NB;
    float* uh = qg + (size_t)T_STEPS * NB;

    uh_kernel<<<dim3((NB + 255) / 256), dim3(256), 0, stream>>>(raw, uh);
    scan_kernel<<<dim3((NB * NMULT) / 64), dim3(64), 0, stream>>>(x, raw, out, qs, qg);
    conv_kernel<<<dim3((NB + 255) / 256, T_STEPS), dim3(256), 0, stream>>>(qs, qg, uh, out);
}

// Round 4
// 222.001 us; speedup vs baseline: 1.9458x; 1.2943x over previous
//
#include <hip/hip_runtime.h>
#include <math.h>

#define T_STEPS 730
#define NB      1000
#define NMULT   8
#define LENF    15
#define NEARZ   1e-5f
#define PD      10      // prefetch depth; 730 = 73 * 10 exactly

// ---------------------------------------------------------------------------
// DPP butterfly sum over each aligned group of 8 lanes, pure VALU:
// quad_perm xor1 (0xB1), quad_perm xor2 (0x4E), row_half_mirror (0x141).
// ---------------------------------------------------------------------------
template <int CTRL>
__device__ __forceinline__ float dpp_mov(float x) {
    int xi = __builtin_bit_cast(int, x);
    int r  = __builtin_amdgcn_update_dpp(0, xi, CTRL, 0xF, 0xF, true);
    return __builtin_bit_cast(float, r);
}
__device__ __forceinline__ float sum8(float v) {
    v += dpp_mov<0xB1>(v);
    v += dpp_mov<0x4E>(v);
    v += dpp_mov<0x141>(v);
    return v;   // all 8 lanes of the group hold the group sum
}

// ---------------------------------------------------------------------------
// Single fused kernel. Block = 64 threads (1 wave) = 8 basins x 8 NMUL.
// Grid = 125 blocks -> 1000 basins.
//
// Phase 1 (scan): 1 thread per (basin, mul) chain; depth-10 rotating register
//   prefetch of x hides the ~900cy cold-HBM load latency. Cross-NMUL means
//   via DPP. qsurf/qgw means -> LDS (for the conv); AET/S/G means -> global.
// Phase 2 (conv): 15-tap gamma-UH causal conv from LDS. Lane = (t-segment,
//   basin); UH weights computed in-register (gammaln cancels under norm).
// ---------------------------------------------------------------------------
__global__ __launch_bounds__(64) void abcd_fused(const float* __restrict__ x,
                                                 const float* __restrict__ raw,
                                                 float* __restrict__ out) {
    __shared__ float qs_lds[T_STEPS * NMULT];   // [t*8 + local_basin]
    __shared__ float qg_lds[T_STEPS * NMULT];

    const int L  = threadIdx.x;
    const int lb = L >> 3;                 // local basin 0..7
    const int m  = L & 7;                  // ensemble member
    const int b  = blockIdx.x * 8 + lb;    // global basin (grid=125 -> b<1000)

    // ---- phase 1: scan ----------------------------------------------------
    // raw layout (B,34) = [a(8), b(8), c(8), d(8), ra, rb]
    const float* rp = raw + b * 34;
    float pa = rp[0 * NMULT + m] * 0.9f + 0.1f;
    float pb = rp[1 * NMULT + m] * 450.0f + 50.0f;
    float pc = rp[2 * NMULT + m];
    float pd = rp[3 * NMULT + m] * 0.89f + 0.01f;

    float inv2a   = 1.0f / (2.0f * pa);
    float pb2a    = pb * inv2a;
    float boa     = pb / pa;
    float ninvbl2 = -1.4426950408889634f / pb;   // exp(-pet/b)=exp2(pet*this)
    float omc     = 1.0f - pc;
    float inv1pd  = 1.0f / (1.0f + pd);

    float S = 50.0f, G = 10.0f;

    const float2* __restrict__ xf = (const float2*)x;   // (T,B) of (p,pet)

    float2 buf[PD];
#pragma unroll
    for (int i = 0; i < PD; ++i) buf[i] = xf[i * NB + b];

    for (int tb = 0; tb < T_STEPS; tb += PD) {
#pragma unroll
        for (int j = 0; j < PD; ++j) {
            const int t = tb + j;
            float2 cur = buf[j];                       // waits vmcnt(~39)
            int tn = t + PD; tn = tn < T_STEPS ? tn : T_STEPS - 1;
            buf[j] = xf[tn * NB + b];                  // refill slot (10 deep)

            float p = cur.x, pet = cur.y;
            float W     = p + S;
            float term  = fmaf(W, inv2a, pb2a);
            float disc  = fmaf(term, term, -W * boa);
            float r     = sqrtf(fmaxf(disc, NEARZ));
            float Y     = term - r;
            float e     = __builtin_amdgcn_exp2f(pet * ninvbl2);
            float Sn    = Y * e;
            float AET   = Y - Sn;
            float avail = W - Y;
            float Qsurf = omc * avail;
            float Gn    = fmaf(pc, avail, G) * inv1pd;
            float Qgw   = pd * Gn;
            S = Sn; G = Gn;

            float r0 = sum8(Qsurf);
            float r1 = sum8(Qgw);
            float r2 = sum8(AET);
            float r3 = sum8(Sn);
            float r4 = sum8(Gn);

            if (m == 0) {
                qs_lds[t * 8 + lb] = r0 * 0.125f;
                qg_lds[t * 8 + lb] = r1 * 0.125f;
                float* o = out + (t * NB + b) * 6;
                o[3] = r2 * 0.125f;
                o[4] = r3 * 0.125f;
                o[5] = r4 * 0.125f;
            }
        }
    }

    __syncthreads();

    // ---- phase 2: gamma-UH convolution from LDS ---------------------------
    // lane -> (conv basin cb, t-segment seg); 8 segments x 92 steps >= 730.
    const int cb  = L & 7;
    const int gb  = blockIdx.x * 8 + cb;
    const int seg = L >> 3;

    // UH weights: w_k ∝ t_k^(aa-1) * exp(-t_k/theta), normalized.
    float ra_ = raw[gb * 34 + 32] * 2.9f;
    float rb_ = raw[gb * 34 + 33] * 6.5f;
    float aa  = fmaxf(ra_, 0.0f) + 0.1f;
    float th  = fmaxf(rb_, 0.0f) + 0.5f;
    float inv_th = 1.0f / th;
    float am1 = aa - 1.0f;
    float w[LENF];
    float sw = 0.0f;
#pragma unroll
    for (int k = 0; k < LENF; ++k) {
        float tt = (float)k + 0.5f;
        w[k] = __expf(am1 * __logf(tt) - tt * inv_th);
        sw += w[k];
    }
    float invs = 1.0f / sw;
#pragma unroll
    for (int k = 0; k < LENF; ++k) w[k] *= invs;

    const int t0 = seg * 92;
    const int t1 = (t0 + 92 < T_STEPS) ? (t0 + 92) : T_STEPS;
    for (int t = t0; t < t1; ++t) {
        float ys = 0.0f, yg = 0.0f;
        if (t >= LENF - 1) {
#pragma unroll
            for (int k = 0; k < LENF; ++k) {
                ys = fmaf(qs_lds[(t - k) * 8 + cb], w[k], ys);
                yg = fmaf(qg_lds[(t - k) * 8 + cb], w[k], yg);
            }
        } else {
            for (int k = 0; k <= t; ++k) {
                ys = fmaf(qs_lds[(t - k) * 8 + cb], w[k], ys);
                yg = fmaf(qg_lds[(t - k) * 8 + cb], w[k], yg);
            }
        }
        float* o = out + (t * NB + gb) * 6;
        o[0] = ys + yg;
        o[1] = ys;
        o[2] = yg;
    }
}

// ---------------------------------------------------------------------------
extern "C" void kernel_launch(void* const* d_in, const int* in_sizes, int n_in,
                              void* d_out, int out_size, void* d_ws, size_t ws_size,
                              hipStream_t stream) {
    const float* x   = (const float*)d_in[0];   // (T,B,2) fp32
    const float* raw = (const float*)d_in[1];   // (B,34)  fp32
    float* out = (float*)d_out;                 // (T,B,6) fp32

    abcd_fused<<<dim3(NB / 8), dim3(64), 0, stream>>>(x, raw, out);
}

// Round 5
// 183.088 us; speedup vs baseline: 2.3593x; 1.2125x over previous
//
#include <hip/hip_runtime.h>
#include <math.h>

#define T_STEPS 730
#define NB      1000
#define LENF    15
#define NEARZ   1e-5f
#define PD      15      // prefetch depth == FIR length; 730 = 48*15 + 10

// ---------------------------------------------------------------------------
// DPP butterfly sum over each aligned group of 8 lanes, pure VALU:
// quad_perm xor1 (0xB1), quad_perm xor2 (0x4E), row_half_mirror (0x141).
// ---------------------------------------------------------------------------
template <int CTRL>
__device__ __forceinline__ float dpp_mov(float x) {
    int xi = __builtin_bit_cast(int, x);
    int r  = __builtin_amdgcn_update_dpp(0, xi, CTRL, 0xF, 0xF, true);
    return __builtin_bit_cast(float, r);
}
__device__ __forceinline__ float sum8(float v) {
    v += dpp_mov<0xB1>(v);
    v += dpp_mov<0x4E>(v);
    v += dpp_mov<0x141>(v);
    return v;   // all 8 lanes of the group hold the group sum
}

// ---------------------------------------------------------------------------
// Single-pass fused scan + streaming FIR routing. Block = 64 = 8 basins x 8
// ensemble members; grid = 125. Per step: 1 float2 load (15-deep register
// prefetch), physics, 5 DPP butterfly sums, lane-role FIR (hist ring with
// compile-time indices via 15-step unroll), 1 global store (lane m writes
// channel m; lanes 6,7 write a dummy ws slot -> fully branchless loop).
// ---------------------------------------------------------------------------
__global__ __launch_bounds__(64) void abcd_fused(const float* __restrict__ x,
                                                 const float* __restrict__ raw,
                                                 float* __restrict__ out,
                                                 float* __restrict__ dummy) {
    const int L  = threadIdx.x;
    const int lb = L >> 3;                 // local basin 0..7
    const int m  = L & 7;                  // ensemble member / channel role
    const int b  = blockIdx.x * 8 + lb;    // global basin

    // raw layout (B,34) = [a(8), b(8), c(8), d(8), ra, rb]
    const float* rp = raw + b * 34;
    float pa = rp[0 * 8 + m] * 0.9f + 0.1f;
    float pb = rp[1 * 8 + m] * 450.0f + 50.0f;
    float pc = rp[2 * 8 + m];
    float pd = rp[3 * 8 + m] * 0.89f + 0.01f;

    float inv2a   = 1.0f / (2.0f * pa);
    float pb2a    = pb * inv2a;
    float boa     = pb / pa;
    float ninvbl2 = -1.4426950408889634f / pb;   // exp(-pet/b)=exp2(pet*this)
    float omc     = 1.0f - pc;
    float inv1pd  = 1.0f / (1.0f + pd);

    // gamma-UH weights (gammaln cancels under normalization); fold the /8
    // ensemble mean and the per-lane channel role into wl[].
    float ra_ = rp[32] * 2.9f;
    float rb_ = rp[33] * 6.5f;
    float aa  = fmaxf(ra_, 0.0f) + 0.1f;
    float th  = fmaxf(rb_, 0.0f) + 0.5f;
    float inv_th = 1.0f / th;
    float am1 = aa - 1.0f;
    float w[LENF];
    float sw = 0.0f;
#pragma unroll
    for (int k = 0; k < LENF; ++k) {
        float tt = (float)k + 0.5f;
        w[k] = __expf(am1 * __logf(tt) - tt * inv_th);
        sw += w[k];
    }
    float invs = 0.125f / sw;   // UH normalization x ensemble mean
    float wl[LENF];
#pragma unroll
    for (int k = 0; k < LENF; ++k) {
        float conv_w = w[k] * invs;                    // lanes 0..2: routed
        float pass_w = (k == 0) ? 0.125f : 0.0f;       // lanes 3..5: mean only
        float v2 = (m >= 3) ? pass_w : conv_w;
        wl[k] = (m >= 6) ? 0.0f : v2;                  // lanes 6,7: inert
    }

    // per-lane output pointer: lane m<6 -> channel m of basin b; else dummy.
    float* optr;
    long long incr;
    if (m < 6) { optr = out + (long long)b * 6 + m; incr = (long long)NB * 6; }
    else       { optr = dummy + (blockIdx.x * 64 + L); incr = 0; }

    float S = 50.0f, G = 10.0f;
    float hist[LENF];
#pragma unroll
    for (int k = 0; k < LENF; ++k) hist[k] = 0.0f;     // causal zero-history

    const float2* __restrict__ xf = (const float2*)x;  // (T,B) of (p,pet)
    float2 buf[PD];
#pragma unroll
    for (int j = 0; j < PD; ++j) buf[j] = xf[j * NB + b];

    // one fully-branchless time step; p = t mod 15 is compile-time constant
    auto step = [&](int t, int p, bool refill) {
        float2 cur = buf[p];
        if (refill) {
            int tn = t + PD; tn = tn < T_STEPS ? tn : T_STEPS - 1;
            buf[p] = xf[tn * NB + b];
        }
        float pcp = cur.x, pet = cur.y;
        float W     = pcp + S;
        float term  = fmaf(W, inv2a, pb2a);
        float disc  = fmaf(term, term, -W * boa);
        float r     = sqrtf(fmaxf(disc, NEARZ));
        float Y     = term - r;
        float e     = __builtin_amdgcn_exp2f(pet * ninvbl2);
        float Sn    = Y * e;
        float AET   = Y - Sn;
        float avail = W - Y;
        float Qs    = omc * avail;
        float Gn    = fmaf(pc, avail, G) * inv1pd;
        float Qg    = pd * Gn;
        S = Sn; G = Gn;

        float qs_s = sum8(Qs);
        float qg_s = sum8(Qg);
        float ae_s = sum8(AET);
        float s_s  = sum8(Sn);
        float g_s  = sum8(Gn);

        float v = qs_s + qg_s;          // lane 0: Qsim series
        v = (m == 1) ? qs_s : v;
        v = (m == 2) ? qg_s : v;
        v = (m == 3) ? ae_s : v;
        v = (m == 4) ? s_s  : v;
        v = (m == 5) ? g_s  : v;

        hist[p] = v;
        float y0 = 0.0f, y1 = 0.0f, y2 = 0.0f;   // 3 chains: break fma latency
#pragma unroll
        for (int k = 0; k < LENF; k += 3) y0 = fmaf(wl[k], hist[(p - k + 30) % LENF], y0);
#pragma unroll
        for (int k = 1; k < LENF; k += 3) y1 = fmaf(wl[k], hist[(p - k + 30) % LENF], y1);
#pragma unroll
        for (int k = 2; k < LENF; k += 3) y2 = fmaf(wl[k], hist[(p - k + 30) % LENF], y2);
        float y = (y0 + y1) + y2;

        *optr = y;
        optr += incr;
    };

    for (int tb = 0; tb < 720; tb += PD) {
#pragma unroll
        for (int j = 0; j < PD; ++j) step(tb + j, j, true);
    }
#pragma unroll
    for (int j = 0; j < 10; ++j) step(720 + j, j, false);   // 720 % 15 == 0
}

// ---------------------------------------------------------------------------
extern "C" void kernel_launch(void* const* d_in, const int* in_sizes, int n_in,
                              void* d_out, int out_size, void* d_ws, size_t ws_size,
                              hipStream_t stream) {
    const float* x   = (const float*)d_in[0];   // (T,B,2) fp32
    const float* raw = (const float*)d_in[1];   // (B,34)  fp32
    float* out = (float*)d_out;                 // (T,B,6) fp32
    float* dummy = (float*)d_ws;                // 32 KB sink for lanes 6,7

    abcd_fused<<<dim3(NB / 8), dim3(64), 0, stream>>>(x, raw, out, dummy);
}

// Round 6
// 182.823 us; speedup vs baseline: 2.3627x; 1.0014x over previous
//
#include <hip/hip_runtime.h>
#include <math.h>

#define T_STEPS 730
#define NB      1000
#define LENF    15
#define NEARZ   1e-5f
#define PD      15      // prefetch depth == FIR length; 730 = 48*15 + 10

// ---------------------------------------------------------------------------
// DPP butterfly sum over each aligned group of 8 lanes, pure VALU:
// quad_perm xor1 (0xB1), quad_perm xor2 (0x4E), row_half_mirror (0x141).
// ---------------------------------------------------------------------------
template <int CTRL>
__device__ __forceinline__ float dpp_mov(float x) {
    int xi = __builtin_bit_cast(int, x);
    int r  = __builtin_amdgcn_update_dpp(0, xi, CTRL, 0xF, 0xF, true);
    return __builtin_bit_cast(float, r);
}
__device__ __forceinline__ float sum8(float v) {
    v += dpp_mov<0xB1>(v);
    v += dpp_mov<0x4E>(v);
    v += dpp_mov<0x141>(v);
    return v;   // all 8 lanes of the group hold the group sum
}

// ---------------------------------------------------------------------------
// Single-pass fused scan + streaming FIR routing. Block = 64 = 8 basins x 8
// ensemble members; grid = 125. Per step: 1 float2 load (15-deep register
// prefetch), physics, 5 DPP butterfly sums, lane-role FIR (hist ring with
// compile-time indices via 15-step unroll), 1 global store (lane m writes
// channel m; lanes 6,7 write a dummy ws slot -> fully branchless loop).
//
// __launch_bounds__(64, 1): 1 wave/SIMD -> full 512-VGPR budget. Without the
// second arg the compiler capped at 64 VGPRs (8-wave occupancy heuristic) and
// spilled buf/hist/wl to scratch -> ~350 stall cyc/step (R4 post-mortem).
// ---------------------------------------------------------------------------
__global__ __launch_bounds__(64, 1) void abcd_fused(const float* __restrict__ x,
                                                    const float* __restrict__ raw,
                                                    float* __restrict__ out,
                                                    float* __restrict__ dummy) {
    const int L  = threadIdx.x;
    const int lb = L >> 3;                 // local basin 0..7
    const int m  = L & 7;                  // ensemble member / channel role
    const int b  = blockIdx.x * 8 + lb;    // global basin

    // raw layout (B,34) = [a(8), b(8), c(8), d(8), ra, rb]
    const float* rp = raw + b * 34;
    float pa = rp[0 * 8 + m] * 0.9f + 0.1f;
    float pb = rp[1 * 8 + m] * 450.0f + 50.0f;
    float pc = rp[2 * 8 + m];
    float pd = rp[3 * 8 + m] * 0.89f + 0.01f;

    float inv2a   = 1.0f / (2.0f * pa);
    float pb2a    = pb * inv2a;
    float boa     = pb / pa;
    float ninvbl2 = -1.4426950408889634f / pb;   // exp(-pet/b)=exp2(pet*this)
    float omc     = 1.0f - pc;
    float inv1pd  = 1.0f / (1.0f + pd);

    // gamma-UH weights (gammaln cancels under normalization); fold the /8
    // ensemble mean and the per-lane channel role into wl[].
    float ra_ = rp[32] * 2.9f;
    float rb_ = rp[33] * 6.5f;
    float aa  = fmaxf(ra_, 0.0f) + 0.1f;
    float th  = fmaxf(rb_, 0.0f) + 0.5f;
    float inv_th = 1.0f / th;
    float am1 = aa - 1.0f;
    float w[LENF];
    float sw = 0.0f;
#pragma unroll
    for (int k = 0; k < LENF; ++k) {
        float tt = (float)k + 0.5f;
        w[k] = __expf(am1 * __logf(tt) - tt * inv_th);
        sw += w[k];
    }
    float invs = 0.125f / sw;   // UH normalization x ensemble mean
    float wl[LENF];
#pragma unroll
    for (int k = 0; k < LENF; ++k) {
        float conv_w = w[k] * invs;                    // lanes 0..2: routed
        float pass_w = (k == 0) ? 0.125f : 0.0f;       // lanes 3..5: mean only
        float v2 = (m >= 3) ? pass_w : conv_w;
        wl[k] = (m >= 6) ? 0.0f : v2;                  // lanes 6,7: inert
    }

    // per-lane output pointer: lane m<6 -> channel m of basin b; else dummy.
    float* optr;
    long long incr;
    if (m < 6) { optr = out + (long long)b * 6 + m; incr = (long long)NB * 6; }
    else       { optr = dummy + (blockIdx.x * 64 + L); incr = 0; }

    float S = 50.0f, G = 10.0f;
    float hist[LENF];
#pragma unroll
    for (int k = 0; k < LENF; ++k) hist[k] = 0.0f;     // causal zero-history

    const float2* __restrict__ xf = (const float2*)x;  // (T,B) of (p,pet)
    float2 buf[PD];
#pragma unroll
    for (int j = 0; j < PD; ++j) buf[j] = xf[j * NB + b];

    // one fully-branchless time step; p = t mod 15 is compile-time constant
    auto step = [&](int t, int p, bool refill) {
        float2 cur = buf[p];
        if (refill) {
            int tn = t + PD; tn = tn < T_STEPS ? tn : T_STEPS - 1;
            buf[p] = xf[tn * NB + b];
        }
        float pcp = cur.x, pet = cur.y;
        float W     = pcp + S;
        float term  = fmaf(W, inv2a, pb2a);
        float disc  = fmaf(term, term, -W * boa);
        float r     = sqrtf(fmaxf(disc, NEARZ));
        float Y     = term - r;
        float e     = __builtin_amdgcn_exp2f(pet * ninvbl2);
        float Sn    = Y * e;
        float AET   = Y - Sn;
        float avail = W - Y;
        float Qs    = omc * avail;
        float Gn    = fmaf(pc, avail, G) * inv1pd;
        float Qg    = pd * Gn;
        S = Sn; G = Gn;

        float qs_s = sum8(Qs);
        float qg_s = sum8(Qg);
        float ae_s = sum8(AET);
        float s_s  = sum8(Sn);
        float g_s  = sum8(Gn);

        float v = qs_s + qg_s;          // lane 0: Qsim series
        v = (m == 1) ? qs_s : v;
        v = (m == 2) ? qg_s : v;
        v = (m == 3) ? ae_s : v;
        v = (m == 4) ? s_s  : v;
        v = (m == 5) ? g_s  : v;

        hist[p] = v;
        float y0 = 0.0f, y1 = 0.0f, y2 = 0.0f;   // 3 chains: break fma latency
#pragma unroll
        for (int k = 0; k < LENF; k += 3) y0 = fmaf(wl[k], hist[(p - k + 30) % LENF], y0);
#pragma unroll
        for (int k = 1; k < LENF; k += 3) y1 = fmaf(wl[k], hist[(p - k + 30) % LENF], y1);
#pragma unroll
        for (int k = 2; k < LENF; k += 3) y2 = fmaf(wl[k], hist[(p - k + 30) % LENF], y2);
        float y = (y0 + y1) + y2;

        *optr = y;
        optr += incr;
    };

    for (int tb = 0; tb < 720; tb += PD) {
#pragma unroll
        for (int j = 0; j < PD; ++j) step(tb + j, j, true);
    }
#pragma unroll
    for (int j = 0; j < 10; ++j) step(720 + j, j, false);   // 720 % 15 == 0
}

// ---------------------------------------------------------------------------
extern "C" void kernel_launch(void* const* d_in, const int* in_sizes, int n_in,
                              void* d_out, int out_size, void* d_ws, size_t ws_size,
                              hipStream_t stream) {
    const float* x   = (const float*)d_in[0];   // (T,B,2) fp32
    const float* raw = (const float*)d_in[1];   // (B,34)  fp32
    float* out = (float*)d_out;                 // (T,B,6) fp32
    float* dummy = (float*)d_ws;                // 32 KB sink for lanes 6,7

    abcd_fused<<<dim3(NB / 8), dim3(64), 0, stream>>>(x, raw, out, dummy);
}

// Round 7
// 149.037 us; speedup vs baseline: 2.8984x; 1.2267x over previous
//
#include <hip/hip_runtime.h>
#include <math.h>

#define T_STEPS 730
#define NB      1000
#define LENF    15
#define NEARZ   1e-5f
#define CHUNK   10      // prefetch chunk; 730 = 73*10; 60 steps = 0 mod 15

// ---------------------------------------------------------------------------
// DPP butterfly sum over each aligned group of 8 lanes, pure VALU:
// quad_perm xor1 (0xB1), quad_perm xor2 (0x4E), row_half_mirror (0x141).
// ---------------------------------------------------------------------------
template <int CTRL>
__device__ __forceinline__ float dpp_mov(float x) {
    int xi = __builtin_bit_cast(int, x);
    int r  = __builtin_amdgcn_update_dpp(0, xi, CTRL, 0xF, 0xF, true);
    return __builtin_bit_cast(float, r);
}
__device__ __forceinline__ float sum8(float v) {
    v += dpp_mov<0xB1>(v);
    v += dpp_mov<0x4E>(v);
    v += dpp_mov<0x141>(v);
    return v;   // all 8 lanes of the group hold the group sum
}

// One physics + reduce + FIR + store step. P must fold to a constant after
// unrolling so hist[] stays register-resident.
#define STEP(CURV, P)                                                          \
  {                                                                            \
    float pcp = (CURV).x, pet = (CURV).y;                                      \
    float W     = pcp + S;                                                     \
    float term  = fmaf(W, inv2a, pb2a);                                        \
    float disc  = fmaf(term, term, -W * boa);                                  \
    float r     = __builtin_amdgcn_sqrtf(fmaxf(disc, NEARZ));                  \
    float Y     = term - r;                                                    \
    float e     = __builtin_amdgcn_exp2f(pet * ninvbl2);                       \
    float Sn    = Y * e;                                                       \
    float AET   = Y - Sn;                                                      \
    float avail = W - Y;                                                       \
    float Qs    = omc * avail;                                                 \
    float Gn    = fmaf(pc, avail, G) * inv1pd;                                 \
    float Qg    = pd * Gn;                                                     \
    S = Sn; G = Gn;                                                            \
    float qs_s = sum8(Qs);                                                     \
    float qg_s = sum8(Qg);                                                     \
    float ae_s = sum8(AET);                                                    \
    float s_s  = sum8(Sn);                                                     \
    float g_s  = sum8(Gn);                                                     \
    float v = qs_s + qg_s;                                                     \
    v = (m == 1) ? qs_s : v;                                                   \
    v = (m == 2) ? qg_s : v;                                                   \
    v = (m == 3) ? ae_s : v;                                                   \
    v = (m == 4) ? s_s  : v;                                                   \
    v = (m == 5) ? g_s  : v;                                                   \
    hist[(P)] = v;                                                             \
    float y0 = 0.0f, y1 = 0.0f, y2 = 0.0f;                                     \
    _Pragma("unroll")                                                          \
    for (int k = 0; k < LENF; k += 3)                                          \
        y0 = fmaf(wl[k], hist[((P) - k + 30) % LENF], y0);                     \
    _Pragma("unroll")                                                          \
    for (int k = 1; k < LENF; k += 3)                                          \
        y1 = fmaf(wl[k], hist[((P) - k + 30) % LENF], y1);                     \
    _Pragma("unroll")                                                          \
    for (int k = 2; k < LENF; k += 3)                                          \
        y2 = fmaf(wl[k], hist[((P) - k + 30) % LENF], y2);                     \
    *optr = (y0 + y1) + y2;                                                    \
    optr += incr;                                                              \
  }

// ---------------------------------------------------------------------------
// Fused scan + streaming FIR. Block = 64 = 8 basins x 8 members; grid = 125.
// A/B double-buffered 10-step chunks: loads for chunk k+1 are issued at the
// top of chunk k and PINNED there by sched_barrier(0) so the scheduler cannot
// sink them to their uses (R5 post-mortem: it collapsed the prefetch to save
// VGPRs -> ~320 stall cyc/step). Load->use gap = 1 chunk > HBM latency.
// ---------------------------------------------------------------------------
__global__ __launch_bounds__(64, 1) void abcd_fused(const float* __restrict__ x,
                                                    const float* __restrict__ raw,
                                                    float* __restrict__ out,
                                                    float* __restrict__ dummy) {
    const int L  = threadIdx.x;
    const int lb = L >> 3;                 // local basin 0..7
    const int m  = L & 7;                  // member / output-channel role
    const int b  = blockIdx.x * 8 + lb;    // global basin

    // raw layout (B,34) = [a(8), b(8), c(8), d(8), ra, rb]
    const float* rp = raw + b * 34;
    float pa = rp[0 * 8 + m] * 0.9f + 0.1f;
    float pb = rp[1 * 8 + m] * 450.0f + 50.0f;
    float pc = rp[2 * 8 + m];
    float pd = rp[3 * 8 + m] * 0.89f + 0.01f;

    float inv2a   = 1.0f / (2.0f * pa);
    float pb2a    = pb * inv2a;
    float boa     = pb / pa;
    float ninvbl2 = -1.4426950408889634f / pb;   // exp(-pet/b)=exp2(pet*this)
    float omc     = 1.0f - pc;
    float inv1pd  = 1.0f / (1.0f + pd);

    // gamma-UH weights (gammaln cancels under normalization); fold the /8
    // ensemble mean and the per-lane channel role into wl[].
    float ra_ = rp[32] * 2.9f;
    float rb_ = rp[33] * 6.5f;
    float aa  = fmaxf(ra_, 0.0f) + 0.1f;
    float th  = fmaxf(rb_, 0.0f) + 0.5f;
    float inv_th = 1.0f / th;
    float am1 = aa - 1.0f;
    float w[LENF];
    float sw = 0.0f;
#pragma unroll
    for (int k = 0; k < LENF; ++k) {
        float tt = (float)k + 0.5f;
        w[k] = __expf(am1 * __logf(tt) - tt * inv_th);
        sw += w[k];
    }
    float invs = 0.125f / sw;   // UH normalization x ensemble mean
    float wl[LENF];
#pragma unroll
    for (int k = 0; k < LENF; ++k) {
        float conv_w = w[k] * invs;                    // lanes 0..2: routed
        float pass_w = (k == 0) ? 0.125f : 0.0f;       // lanes 3..5: mean only
        float v2 = (m >= 3) ? pass_w : conv_w;
        wl[k] = (m >= 6) ? 0.0f : v2;                  // lanes 6,7: inert
    }

    // per-lane output pointer: lane m<6 -> channel m of basin b; else dummy.
    float* optr;
    long long incr;
    if (m < 6) { optr = out + (long long)b * 6 + m; incr = (long long)NB * 6; }
    else       { optr = dummy + (blockIdx.x * 64 + L); incr = 0; }

    float S = 50.0f, G = 10.0f;
    float hist[LENF];
#pragma unroll
    for (int k = 0; k < LENF; ++k) hist[k] = 0.0f;     // causal zero-history

    const float2* __restrict__ xf = (const float2*)x;  // (T,B) of (p,pet)

    float2 A[CHUNK], B[CHUNK];
#pragma unroll
    for (int j = 0; j < CHUNK; ++j) A[j] = xf[j * NB + b];   // chunk 0

    // 12 outer iterations x 6 chunks (60 steps, == 0 mod 15) + 10-step tail.
    for (int i = 0; i < 12; ++i) {
        const int tb = 60 * i;
#pragma unroll
        for (int c = 0; c < 6; ++c) {
            float2* CUR = (c & 1) ? B : A;     // folds at compile time
            float2* NXT = (c & 1) ? A : B;
            // prefetch chunk (6i + c + 1); last is chunk 72 (t=720..729)
#pragma unroll
            for (int j = 0; j < CHUNK; ++j)
                NXT[j] = xf[(tb + CHUNK * (c + 1) + j) * NB + b];
            __builtin_amdgcn_sched_barrier(0);  // pin loads above the steps
#pragma unroll
            for (int j = 0; j < CHUNK; ++j) {
                STEP(CUR[j], ((CHUNK * c + j) % LENF));
            }
        }
    }
    // tail: chunk 72 already resident in A (720 % 15 == 0 -> phase = j)
#pragma unroll
    for (int j = 0; j < CHUNK; ++j) {
        STEP(A[j], (j));
    }
}

// ---------------------------------------------------------------------------
extern "C" void kernel_launch(void* const* d_in, const int* in_sizes, int n_in,
                              void* d_out, int out_size, void* d_ws, size_t ws_size,
                              hipStream_t stream) {
    const float* x   = (const float*)d_in[0];   // (T,B,2) fp32
    const float* raw = (const float*)d_in[1];   // (B,34)  fp32
    float* out = (float*)d_out;                 // (T,B,6) fp32
    float* dummy = (float*)d_ws;                // 32 KB sink for lanes 6,7

    abcd_fused<<<dim3(NB / 8), dim3(64), 0, stream>>>(x, raw, out, dummy);
}